// Round 1
// baseline (3697.107 us; speedup 1.0000x reference)
//
#include <hip/hip_runtime.h>

#define HW 4096

// ---------------------------------------------------------------------------
// Direct 3x3 SAME conv, 64x64 spatial, fp32.
// Block: 256 threads = 16 (co/4) x 16 (pix/4). Tile: 64 outC x 64 pixels (one row).
// MODE 0: value conv  -> NHWC out (img, 4096, 256), + bias, * !mask
// MODE 1: off+attn    -> NHWC out (n, 4096, 288): co<192 from w0/b0 (off), else w1/b1 (attn)
// MODE 2: out conv    -> NCHW out (n, 256, 4096) + bias (final output)
// ---------------------------------------------------------------------------
template<int CIN, int MODE>
__global__ __launch_bounds__(256) void conv3x3_kernel(
    const float* __restrict__ in,
    const float* __restrict__ w0,
    const float* __restrict__ b0,
    const float* __restrict__ w1,
    const float* __restrict__ b1,
    const unsigned char* __restrict__ mask,
    float* __restrict__ out,
    int cout_total)
{
    const int y   = blockIdx.x;   // output row 0..63
    const int cot = blockIdx.y;   // co tile
    const int img = blockIdx.z;

    const int tid  = threadIdx.x;
    const int tpix = tid & 15;
    const int tco  = tid >> 4;
    const int x0   = tpix * 4;

    __shared__ float ilds[8][3][66];   // ci, row, col(-1..64)
    __shared__ float wlds[8][9][64];   // ci, tap, co

    float acc[4][4];
    #pragma unroll
    for (int i = 0; i < 4; ++i)
        #pragma unroll
        for (int j = 0; j < 4; ++j) acc[i][j] = 0.f;

    const int co_base = cot * 64;

    for (int chunk = 0; chunk < CIN / 8; ++chunk) {
        const int ci0 = chunk * 8;
        __syncthreads();
        // stage input: 8 ci x 3 rows x 66 cols (zero-padded halo)
        for (int e = tid; e < 8 * 3 * 66; e += 256) {
            int ci  = e / 198;
            int r   = (e % 198) / 66;
            int col = e % 66;
            int xx = col - 1;
            int yy = y + r - 1;
            float v = 0.f;
            if (xx >= 0 && xx < 64 && yy >= 0 && yy < 64)
                v = in[((size_t)img * CIN + (ci0 + ci)) * HW + yy * 64 + xx];
            ilds[ci][r][col] = v;
        }
        // stage weights: 64 co x 8 ci x 9 taps (global OIHW -> lds [ci][tap][co])
        for (int e = tid; e < 64 * 72; e += 256) {
            int co  = e / 72;
            int r   = e % 72;
            int ci  = r / 9;
            int tap = r % 9;
            int co_g = co_base + co;
            float v = 0.f;
            if (MODE == 1) {
                if (co_g < 192)
                    v = w0[((size_t)co_g * CIN + (ci0 + ci)) * 9 + tap];
                else if (co_g < cout_total)
                    v = w1[((size_t)(co_g - 192) * CIN + (ci0 + ci)) * 9 + tap];
            } else {
                v = w0[((size_t)co_g * CIN + (ci0 + ci)) * 9 + tap];
            }
            wlds[ci][tap][co] = v;
        }
        __syncthreads();

        for (int ci = 0; ci < 8; ++ci) {
            float rin[3][6];
            #pragma unroll
            for (int r = 0; r < 3; ++r)
                #pragma unroll
                for (int j = 0; j < 6; ++j)
                    rin[r][j] = ilds[ci][r][x0 + j];
            #pragma unroll
            for (int ky = 0; ky < 3; ++ky)
                #pragma unroll
                for (int kx = 0; kx < 3; ++kx) {
                    const float4 w4 = *(const float4*)&wlds[ci][ky * 3 + kx][tco * 4];
                    #pragma unroll
                    for (int j = 0; j < 4; ++j) {
                        float iv = rin[ky][kx + j];
                        acc[0][j] = fmaf(w4.x, iv, acc[0][j]);
                        acc[1][j] = fmaf(w4.y, iv, acc[1][j]);
                        acc[2][j] = fmaf(w4.z, iv, acc[2][j]);
                        acc[3][j] = fmaf(w4.w, iv, acc[3][j]);
                    }
                }
        }
    }

    const int co_g0 = co_base + tco * 4;
    if (MODE == 0) {
        int n = img / 3, l = img % 3;
        float b0v = b0[co_g0], b1v = b0[co_g0 + 1], b2v = b0[co_g0 + 2], b3v = b0[co_g0 + 3];
        #pragma unroll
        for (int j = 0; j < 4; ++j) {
            int pix = y * 64 + x0 + j;
            float m = mask[(size_t)n * (3 * HW) + l * HW + pix] ? 0.f : 1.f;
            float4 v;
            v.x = (acc[0][j] + b0v) * m;
            v.y = (acc[1][j] + b1v) * m;
            v.z = (acc[2][j] + b2v) * m;
            v.w = (acc[3][j] + b3v) * m;
            *(float4*)&out[((size_t)img * HW + pix) * 256 + co_g0] = v;
        }
    } else if (MODE == 1) {
        if (co_g0 < cout_total) {
            float bb[4];
            #pragma unroll
            for (int i = 0; i < 4; ++i) {
                int cg = co_g0 + i;
                bb[i] = (cg < 192) ? b0[cg] : b1[cg - 192];
            }
            #pragma unroll
            for (int j = 0; j < 4; ++j) {
                int pix = y * 64 + x0 + j;
                float4 v;
                v.x = acc[0][j] + bb[0];
                v.y = acc[1][j] + bb[1];
                v.z = acc[2][j] + bb[2];
                v.w = acc[3][j] + bb[3];
                *(float4*)&out[((size_t)img * HW + pix) * 288 + co_g0] = v;
            }
        }
    } else {
        #pragma unroll
        for (int i = 0; i < 4; ++i) {
            int cg = co_g0 + i;
            float bv = b0[cg];
            float4 v;
            v.x = acc[i][0] + bv;
            v.y = acc[i][1] + bv;
            v.z = acc[i][2] + bv;
            v.w = acc[i][3] + bv;
            *(float4*)&out[((size_t)img * 256 + cg) * HW + y * 64 + x0] = v;
        }
    }
}

// ---------------------------------------------------------------------------
// Deformable sampling core.
// Block: 256 threads = 256 channels (hd = tid>>5, d = tid&31), QB=8 queries.
// value   : (12, 4096, 256) NHWC    offattn : (4, 4096, 288) [0:192)=off (hd,l,p,xy), [192:288)=attn
// refp    : (4, 4096, 3, 2)         out     : (4, 256, 4096) NCHW
// ---------------------------------------------------------------------------
__global__ __launch_bounds__(256) void msda_core_kernel(
    const float* __restrict__ value,
    const float* __restrict__ offattn,
    const float* __restrict__ refp,
    float* __restrict__ out)
{
    constexpr int QB = 8;
    const int n   = blockIdx.y;
    const int q0  = blockIdx.x * QB;
    const int tid = threadIdx.x;
    const int hd  = tid >> 5;

    __shared__ float s_oa[QB][288];
    __shared__ float s_ref[QB][6];
    __shared__ float s_aw[QB][96];

    for (int e = tid; e < QB * 288; e += 256) {
        int qq = e / 288, c = e % 288;
        s_oa[qq][c] = offattn[((size_t)n * HW + q0 + qq) * 288 + c];
    }
    if (tid < QB * 6) {
        int qq = tid / 6, r = tid % 6;
        s_ref[qq][r] = refp[((size_t)n * HW + q0 + qq) * 6 + r];
    }
    __syncthreads();

    // softmax over L*P=12 per (query, head): 64 worker threads
    if (tid < QB * 8) {
        int qq = tid >> 3, h = tid & 7;
        const float* a = &s_oa[qq][192 + h * 12];
        float mx = a[0];
        #pragma unroll
        for (int k = 1; k < 12; ++k) mx = fmaxf(mx, a[k]);
        float e[12];
        float sum = 0.f;
        #pragma unroll
        for (int k = 0; k < 12; ++k) { e[k] = __expf(a[k] - mx); sum += e[k]; }
        float inv = 1.f / sum;
        #pragma unroll
        for (int k = 0; k < 12; ++k) s_aw[qq][h * 12 + k] = e[k] * inv;
    }
    __syncthreads();

    float accq[QB];
    #pragma unroll
    for (int qq = 0; qq < QB; ++qq) accq[qq] = 0.f;

    #pragma unroll
    for (int qq = 0; qq < QB; ++qq) {
        for (int l = 0; l < 3; ++l) {
            const float* vbase = value + ((size_t)(n * 3 + l) * HW) * 256 + tid;
            float rx = s_ref[qq][l * 2 + 0] * 64.f - 0.5f;
            float ry = s_ref[qq][l * 2 + 1] * 64.f - 0.5f;
            #pragma unroll
            for (int p = 0; p < 4; ++p) {
                int idx = hd * 12 + l * 4 + p;
                float x = rx + s_oa[qq][idx * 2 + 0];
                float y = ry + s_oa[qq][idx * 2 + 1];
                float aw = s_aw[qq][idx];
                float xf = floorf(x), yf = floorf(y);
                float lx = x - xf, ly = y - yf;
                int xi = (int)xf, yi = (int)yf;
                float w00 = (1.f - lx) * (1.f - ly) * aw;
                float w10 = lx * (1.f - ly) * aw;
                float w01 = (1.f - lx) * ly * aw;
                float w11 = lx * ly * aw;
                bool vx0 = (xi >= 0) && (xi < 64);
                bool vx1 = (xi + 1 >= 0) && (xi + 1 < 64);
                if (yi >= 0 && yi < 64) {
                    int row = yi * 64;
                    if (vx0) accq[qq] = fmaf(w00, vbase[(size_t)(row + xi) * 256], accq[qq]);
                    if (vx1) accq[qq] = fmaf(w10, vbase[(size_t)(row + xi + 1) * 256], accq[qq]);
                }
                if (yi + 1 >= 0 && yi + 1 < 64) {
                    int row = (yi + 1) * 64;
                    if (vx0) accq[qq] = fmaf(w01, vbase[(size_t)(row + xi) * 256], accq[qq]);
                    if (vx1) accq[qq] = fmaf(w11, vbase[(size_t)(row + xi + 1) * 256], accq[qq]);
                }
            }
        }
    }

    float* obase = out + ((size_t)n * 256 + tid) * HW + q0;
    float4 v0 = {accq[0], accq[1], accq[2], accq[3]};
    float4 v1 = {accq[4], accq[5], accq[6], accq[7]};
    *(float4*)&obase[0] = v0;
    *(float4*)&obase[4] = v1;
}

extern "C" void kernel_launch(void* const* d_in, const int* in_sizes, int n_in,
                              void* d_out, int out_size, void* d_ws, size_t ws_size,
                              hipStream_t stream) {
    const float* query   = (const float*)d_in[0];   // (4,3,256,64,64) == (4,768,64,64)
    const float* refp    = (const float*)d_in[1];   // (4,4096,3,2)
    const float* inflat  = (const float*)d_in[2];   // (4,3,256,64,64) == (12,256,64,64)
    const unsigned char* mask = (const unsigned char*)d_in[5]; // (4, 3*4096) bool
    const float* w_value = (const float*)d_in[6];
    const float* b_value = (const float*)d_in[7];
    const float* w_off   = (const float*)d_in[8];
    const float* b_off   = (const float*)d_in[9];
    const float* w_attn  = (const float*)d_in[10];
    const float* b_attn  = (const float*)d_in[11];
    const float* w_out   = (const float*)d_in[12];
    const float* b_out   = (const float*)d_in[13];

    float* value   = (float*)d_ws;                          // 12*4096*256 f32 = 50.3MB
    float* offattn = value + (size_t)12 * 4096 * 256;       // 4*4096*288 f32  = 18.9MB
    float* core    = offattn + (size_t)4 * 4096 * 288;      // 4*256*4096 f32  = 16.8MB
    float* outp    = (float*)d_out;                         // (4,256,64,64) f32

    dim3 blk(256);
    // 1) value conv: 12 images, Cin=256, Cout=256, NHWC out + mask
    conv3x3_kernel<256, 0><<<dim3(64, 4, 12), blk, 0, stream>>>(
        inflat, w_value, b_value, nullptr, nullptr, mask, value, 256);
    // 2) fused offset+attention conv: 4 images, Cin=768, Cout=288 (192 off + 96 attn)
    conv3x3_kernel<768, 1><<<dim3(64, 5, 4), blk, 0, stream>>>(
        query, w_off, b_off, w_attn, b_attn, nullptr, offattn, 288);
    // 3) deformable sampling + softmax -> NCHW core output
    msda_core_kernel<<<dim3(4096 / 8, 4), blk, 0, stream>>>(value, offattn, refp, core);
    // 4) output conv -> d_out
    conv3x3_kernel<256, 2><<<dim3(64, 4, 4), blk, 0, stream>>>(
        core, w_out, b_out, nullptr, nullptr, nullptr, outp, 256);
}

// Round 4
// 1004.082 us; speedup vs baseline: 3.6821x; 3.6821x over previous
//
#include <hip/hip_runtime.h>

#define HW 4096
typedef __bf16 bf16_t;
typedef _Float16 f16_t;
typedef __bf16 bf16x8 __attribute__((ext_vector_type(8)));
typedef float  f32x4  __attribute__((ext_vector_type(4)));

// ---------------------------------------------------------------------------
// Weight prep: OIHW fp32 -> [tap][co(COPAD)][ci] bf16 (co>=COTOT zero-padded).
// MODE1 merges w_off (CO0 rows) and w_attn (COTOT-CO0 rows).
// ---------------------------------------------------------------------------
__global__ void prep_w(const float* __restrict__ w0, const float* __restrict__ w1,
                       bf16_t* __restrict__ out, int CIN, int CO0, int COTOT, int COPAD)
{
    int idx = blockIdx.x * 256 + threadIdx.x;
    if (idx >= COPAD * CIN) return;
    int co = idx / CIN, ci = idx % CIN;
    #pragma unroll
    for (int tap = 0; tap < 9; ++tap) {
        float v = 0.f;
        if (co < CO0)        v = w0[((size_t)co * CIN + ci) * 9 + tap];
        else if (co < COTOT) v = w1[((size_t)(co - CO0) * CIN + ci) * 9 + tap];
        out[((size_t)tap * COPAD + co) * CIN + ci] = (bf16_t)v;
    }
}

// ---------------------------------------------------------------------------
// NCHW fp32 -> zero-padded (66x66) NHWC bf16. Borders pre-zeroed by memset.
// ---------------------------------------------------------------------------
__global__ __launch_bounds__(256) void pad_nchw_to_nhwc(
    const float* __restrict__ in, bf16_t* __restrict__ out, int C)
{
    const int y = blockIdx.x, ct = blockIdx.y, img = blockIdx.z;
    const int tid = threadIdx.x;
    __shared__ float t[64][65];

    int c = tid >> 2, x0 = (tid & 3) * 16;
    const float* srcc = in + ((size_t)img * C + ct * 64 + c) * HW + y * 64 + x0;
    #pragma unroll
    for (int j = 0; j < 4; ++j) {
        float4 v = *(const float4*)&srcc[j * 4];
        t[c][x0 + j * 4 + 0] = v.x; t[c][x0 + j * 4 + 1] = v.y;
        t[c][x0 + j * 4 + 2] = v.z; t[c][x0 + j * 4 + 3] = v.w;
    }
    __syncthreads();
    int x = tid >> 2, cg = (tid & 3) * 16;
    bf16_t tmp[16];
    #pragma unroll
    for (int j = 0; j < 16; ++j) tmp[j] = (bf16_t)t[cg + j][x];
    // BUG FIX (R3->R4): img offset was missing -> all images wrote image 0.
    bf16_t* dst = &out[((size_t)img * 4356 + (size_t)((y + 1) * 66 + (x + 1))) * C + ct * 64 + cg];
    *(bf16x8*)dst       = *(bf16x8*)&tmp[0];
    *((bf16x8*)dst + 1) = *(bf16x8*)&tmp[8];
}

// ---------------------------------------------------------------------------
// Implicit-GEMM 3x3 conv via bf16 MFMA. Tile: 128 pixels x 64 cout, BK=64,
// K loop = 9 taps x Cin/64. 4 waves (2M x 2N). Register-staged double-buffered
// LDS; XOR quadrant swizzle applied on BOTH ds_write and ds_read (involution
// q ^= p&7) -> conflict-free-to-2-way.
// MODE 0: -> value NHWC bf16 [img][4096][256], +bias, *!mask
// MODE 1: -> offattn f16 [n][4096][288] (co<192 bias0, else bias1)
// MODE 2: swapped operands -> d_out NCHW f32 (+bias), coalesced stores
// ---------------------------------------------------------------------------
template<int CIN, int MODE>
__global__ __launch_bounds__(256) void mfma_conv(
    const bf16_t* __restrict__ Apad,   // [img][66*66][CIN]
    const bf16_t* __restrict__ Wprep,  // [9][COPAD][CIN]
    const float* __restrict__ bias0,
    const float* __restrict__ bias1,
    const unsigned char* __restrict__ mask,
    void* __restrict__ outp)
{
    constexpr int NCHUNK = CIN / 64;
    constexpr int NT = 9 * NCHUNK;
    constexpr int COPAD = (MODE == 1) ? 320 : 256;

    const int bx = blockIdx.x;   // pixel tile (2 output rows)
    const int by = blockIdx.y;   // co tile
    const int img = blockIdx.z;

    const int tid = threadIdx.x;
    const int l = tid & 63;
    const int w = tid >> 6;
    const int wm = w >> 1, wn = w & 1;
    const int y0 = bx * 2;

    __shared__ bf16_t ldsA[2][128 * 64];
    __shared__ bf16_t ldsB[2][64 * 64];

    // A: 4 chunks/thread: slot s -> pixel-row p, K-quadrant q (8 bf16 each)
    int pA[4], qA[4];
    #pragma unroll
    for (int c = 0; c < 4; ++c) {
        int s = (w * 4 + c) * 64 + l;
        pA[c] = s >> 3;
        qA[c] = s & 7;
    }
    int pB[2], qB[2];
    #pragma unroll
    for (int c = 0; c < 2; ++c) {
        int s = (w * 2 + c) * 64 + l;
        pB[c] = s >> 3;
        qB[c] = s & 7;
    }

    const bf16_t* Aimg = Apad + (size_t)img * (66 * 66) * CIN;

    f32x4 acc[4][2];
    #pragma unroll
    for (int m = 0; m < 4; ++m)
        #pragma unroll
        for (int n = 0; n < 2; ++n) acc[m][n] = (f32x4){0.f, 0.f, 0.f, 0.f};

    float4 rA[4], rB[2];

    auto loadT = [&](int t) {
        int tap = t / NCHUNK;
        int ci0 = (t % NCHUNK) * 64;
        int dy = tap / 3, dx = tap % 3;
        #pragma unroll
        for (int c = 0; c < 4; ++c) {
            int yy = y0 + (pA[c] >> 6) + dy;
            int xx = (pA[c] & 63) + dx;
            rA[c] = *(const float4*)(Aimg + ((size_t)(yy * 66 + xx)) * CIN + ci0 + qA[c] * 8);
        }
        #pragma unroll
        for (int c = 0; c < 2; ++c)
            rB[c] = *(const float4*)(Wprep + ((size_t)tap * COPAD + by * 64 + pB[c]) * CIN + ci0 + qB[c] * 8);
    };
    auto writeT = [&](int buf) {
        #pragma unroll
        for (int c = 0; c < 4; ++c)
            *(float4*)&ldsA[buf][pA[c] * 64 + ((qA[c] ^ (pA[c] & 7)) * 8)] = rA[c];
        #pragma unroll
        for (int c = 0; c < 2; ++c)
            *(float4*)&ldsB[buf][pB[c] * 64 + ((qB[c] ^ (pB[c] & 7)) * 8)] = rB[c];
    };

    auto rdA = [&](int buf, int m, int kk) -> bf16x8 {
        int p = wm * 64 + m * 16 + (l & 15);
        int q = kk * 4 + (l >> 4);
        float4 v = *(const float4*)&ldsA[buf][p * 64 + ((q ^ (p & 7)) * 8)];
        return __builtin_bit_cast(bf16x8, v);
    };
    auto rdB = [&](int buf, int n, int kk) -> bf16x8 {
        int r = wn * 32 + n * 16 + (l & 15);
        int q = kk * 4 + (l >> 4);
        float4 v = *(const float4*)&ldsB[buf][r * 64 + ((q ^ (r & 7)) * 8)];
        return __builtin_bit_cast(bf16x8, v);
    };

    loadT(0);
    writeT(0);
    __syncthreads();
    int buf = 0;
    for (int t = 0; t < NT; ++t) {
        if (t + 1 < NT) loadT(t + 1);   // issue next-tile global loads early
        #pragma unroll
        for (int kk = 0; kk < 2; ++kk) {
            bf16x8 a0 = rdA(buf, 0, kk), a1 = rdA(buf, 1, kk);
            bf16x8 a2 = rdA(buf, 2, kk), a3 = rdA(buf, 3, kk);
            bf16x8 b0 = rdB(buf, 0, kk), b1 = rdB(buf, 1, kk);
            if constexpr (MODE == 2) {
                acc[0][0] = __builtin_amdgcn_mfma_f32_16x16x32_bf16(b0, a0, acc[0][0], 0, 0, 0);
                acc[0][1] = __builtin_amdgcn_mfma_f32_16x16x32_bf16(b1, a0, acc[0][1], 0, 0, 0);
                acc[1][0] = __builtin_amdgcn_mfma_f32_16x16x32_bf16(b0, a1, acc[1][0], 0, 0, 0);
                acc[1][1] = __builtin_amdgcn_mfma_f32_16x16x32_bf16(b1, a1, acc[1][1], 0, 0, 0);
                acc[2][0] = __builtin_amdgcn_mfma_f32_16x16x32_bf16(b0, a2, acc[2][0], 0, 0, 0);
                acc[2][1] = __builtin_amdgcn_mfma_f32_16x16x32_bf16(b1, a2, acc[2][1], 0, 0, 0);
                acc[3][0] = __builtin_amdgcn_mfma_f32_16x16x32_bf16(b0, a3, acc[3][0], 0, 0, 0);
                acc[3][1] = __builtin_amdgcn_mfma_f32_16x16x32_bf16(b1, a3, acc[3][1], 0, 0, 0);
            } else {
                acc[0][0] = __builtin_amdgcn_mfma_f32_16x16x32_bf16(a0, b0, acc[0][0], 0, 0, 0);
                acc[0][1] = __builtin_amdgcn_mfma_f32_16x16x32_bf16(a0, b1, acc[0][1], 0, 0, 0);
                acc[1][0] = __builtin_amdgcn_mfma_f32_16x16x32_bf16(a1, b0, acc[1][0], 0, 0, 0);
                acc[1][1] = __builtin_amdgcn_mfma_f32_16x16x32_bf16(a1, b1, acc[1][1], 0, 0, 0);
                acc[2][0] = __builtin_amdgcn_mfma_f32_16x16x32_bf16(a2, b0, acc[2][0], 0, 0, 0);
                acc[2][1] = __builtin_amdgcn_mfma_f32_16x16x32_bf16(a2, b1, acc[2][1], 0, 0, 0);
                acc[3][0] = __builtin_amdgcn_mfma_f32_16x16x32_bf16(a3, b0, acc[3][0], 0, 0, 0);
                acc[3][1] = __builtin_amdgcn_mfma_f32_16x16x32_bf16(a3, b1, acc[3][1], 0, 0, 0);
            }
        }
        if (t + 1 < NT) writeT(buf ^ 1);  // implicit vmcnt wait on rA/rB
        __syncthreads();
        buf ^= 1;
    }

    // epilogue
    #pragma unroll
    for (int m = 0; m < 4; ++m)
        #pragma unroll
        for (int n = 0; n < 2; ++n) {
            f32x4 fr = acc[m][n];
            if constexpr (MODE == 2) {
                int co = by * 64 + wn * 32 + n * 16 + (l >> 4) * 4;
                int pix = bx * 128 + wm * 64 + m * 16 + (l & 15);
                float* op = (float*)outp;
                #pragma unroll
                for (int r = 0; r < 4; ++r)
                    op[((size_t)img * 256 + co + r) * HW + pix] = fr[r] + bias0[co + r];
            } else {
                int pix = bx * 128 + wm * 64 + m * 16 + (l >> 4) * 4;
                int co = by * 64 + wn * 32 + n * 16 + (l & 15);
                if constexpr (MODE == 0) {
                    bf16_t* op = (bf16_t*)outp;
                    float bv = bias0[co];
                    #pragma unroll
                    for (int r = 0; r < 4; ++r) {
                        int p = pix + r;
                        float vv = fr[r] + bv;
                        if (mask[(size_t)img * HW + p]) vv = 0.f;
                        op[((size_t)img * HW + p) * 256 + co] = (bf16_t)vv;
                    }
                } else {
                    if (co < 288) {
                        f16_t* op = (f16_t*)outp;
                        float bv = (co < 192) ? bias0[co] : bias1[co - 192];
                        #pragma unroll
                        for (int r = 0; r < 4; ++r)
                            op[((size_t)img * HW + pix + r) * 288 + co] = (f16_t)(fr[r] + bv);
                    }
                }
            }
        }
}

// ---------------------------------------------------------------------------
// Deformable sampling core. 256 threads = 256 channels, QB=8 queries.
// value bf16 [12][4096][256]; offattn f16 [4][4096][288]; writes padded NHWC
// bf16 [4][66*66][256] (interior only; borders pre-zeroed).
// ---------------------------------------------------------------------------
__global__ __launch_bounds__(256) void msda_core_kernel(
    const bf16_t* __restrict__ value,
    const f16_t* __restrict__ offattn,
    const float* __restrict__ refp,
    bf16_t* __restrict__ outpad)
{
    constexpr int QB = 8;
    const int n   = blockIdx.y;
    const int q0  = blockIdx.x * QB;
    const int tid = threadIdx.x;
    const int hd  = tid >> 5;

    __shared__ float s_oa[QB][288];
    __shared__ float s_ref[QB][6];
    __shared__ float s_aw[QB][96];

    for (int e = tid; e < QB * 288; e += 256) {
        int qq = e / 288, c = e % 288;
        s_oa[qq][c] = (float)offattn[((size_t)n * HW + q0 + qq) * 288 + c];
    }
    if (tid < QB * 6) {
        int qq = tid / 6, r = tid % 6;
        s_ref[qq][r] = refp[((size_t)n * HW + q0 + qq) * 6 + r];
    }
    __syncthreads();

    if (tid < QB * 8) {
        int qq = tid >> 3, h = tid & 7;
        const float* a = &s_oa[qq][192 + h * 12];
        float mx = a[0];
        #pragma unroll
        for (int k = 1; k < 12; ++k) mx = fmaxf(mx, a[k]);
        float e[12]; float sum = 0.f;
        #pragma unroll
        for (int k = 0; k < 12; ++k) { e[k] = __expf(a[k] - mx); sum += e[k]; }
        float inv = 1.f / sum;
        #pragma unroll
        for (int k = 0; k < 12; ++k) s_aw[qq][h * 12 + k] = e[k] * inv;
    }
    __syncthreads();

    float accq[QB];
    #pragma unroll
    for (int qq = 0; qq < QB; ++qq) accq[qq] = 0.f;

    #pragma unroll
    for (int qq = 0; qq < QB; ++qq) {
        for (int ll = 0; ll < 3; ++ll) {
            const bf16_t* vbase = value + ((size_t)(n * 3 + ll) * HW) * 256 + tid;
            float rx = s_ref[qq][ll * 2 + 0] * 64.f - 0.5f;
            float ry = s_ref[qq][ll * 2 + 1] * 64.f - 0.5f;
            #pragma unroll
            for (int p = 0; p < 4; ++p) {
                int idx = hd * 12 + ll * 4 + p;
                float x = rx + s_oa[qq][idx * 2 + 0];
                float y = ry + s_oa[qq][idx * 2 + 1];
                float aw = s_aw[qq][idx];
                float xf = floorf(x), yf = floorf(y);
                float lx = x - xf, ly = y - yf;
                int xi = (int)xf, yi = (int)yf;
                float w00 = (1.f - lx) * (1.f - ly) * aw;
                float w10 = lx * (1.f - ly) * aw;
                float w01 = (1.f - lx) * ly * aw;
                float w11 = lx * ly * aw;
                bool vx0 = (xi >= 0) && (xi < 64);
                bool vx1 = (xi + 1 >= 0) && (xi + 1 < 64);
                if (yi >= 0 && yi < 64) {
                    int row = yi * 64;
                    if (vx0) accq[qq] = fmaf(w00, (float)vbase[(size_t)(row + xi) * 256], accq[qq]);
                    if (vx1) accq[qq] = fmaf(w10, (float)vbase[(size_t)(row + xi + 1) * 256], accq[qq]);
                }
                if (yi + 1 >= 0 && yi + 1 < 64) {
                    int row = (yi + 1) * 64;
                    if (vx0) accq[qq] = fmaf(w01, (float)vbase[(size_t)(row + xi) * 256], accq[qq]);
                    if (vx1) accq[qq] = fmaf(w11, (float)vbase[(size_t)(row + xi + 1) * 256], accq[qq]);
                }
            }
        }
    }

    #pragma unroll
    for (int qq = 0; qq < QB; ++qq) {
        int pix = q0 + qq;
        int pp = ((pix >> 6) + 1) * 66 + (pix & 63) + 1;
        outpad[((size_t)n * 4356 + pp) * 256 + tid] = (bf16_t)accq[qq];
    }
}

extern "C" void kernel_launch(void* const* d_in, const int* in_sizes, int n_in,
                              void* d_out, int out_size, void* d_ws, size_t ws_size,
                              hipStream_t stream) {
    const float* query   = (const float*)d_in[0];
    const float* refp    = (const float*)d_in[1];
    const float* inflat  = (const float*)d_in[2];
    const unsigned char* mask = (const unsigned char*)d_in[5];
    const float* w_value = (const float*)d_in[6];
    const float* b_value = (const float*)d_in[7];
    const float* w_off   = (const float*)d_in[8];
    const float* b_off   = (const float*)d_in[9];
    const float* w_attn  = (const float*)d_in[10];
    const float* b_attn  = (const float*)d_in[11];
    const float* w_out   = (const float*)d_in[12];
    const float* b_out   = (const float*)d_in[13];

    char* ws = (char*)d_ws;
    bf16_t* A_val  = (bf16_t*)ws;  ws += (size_t)12 * 4356 * 256 * 2;  // 26.76 MB
    bf16_t* A_qry  = (bf16_t*)ws;  ws += (size_t)4 * 4356 * 768 * 2;   // 26.76 MB
    bf16_t* A_core = (bf16_t*)ws;  ws += (size_t)4 * 4356 * 256 * 2;   // 8.92 MB
    size_t pad_bytes = (size_t)(12 * 4356 * 256 + 4 * 4356 * 768 + 4 * 4356 * 256) * 2;
    bf16_t* W_val  = (bf16_t*)ws;  ws += (size_t)9 * 256 * 256 * 2;
    bf16_t* W_off  = (bf16_t*)ws;  ws += (size_t)9 * 320 * 768 * 2;
    bf16_t* W_out  = (bf16_t*)ws;  ws += (size_t)9 * 256 * 256 * 2;
    f16_t*  offattn = (f16_t*)ws;  ws += (size_t)4 * 4096 * 288 * 2;   // 9.44 MB
    bf16_t* value  = A_qry;  // reuse: off-conv consumes A_qry before value conv writes
    // total ws: 75.0 MiB  (< 82 MiB proven available by round 1)

    // zero padded-A borders (interiors are overwritten each call)
    hipMemsetAsync(d_ws, 0, pad_bytes, stream);

    prep_w<<<(256 * 256 + 255) / 256, 256, 0, stream>>>(w_value, nullptr, W_val, 256, 256, 256, 256);
    prep_w<<<(320 * 768 + 255) / 256, 256, 0, stream>>>(w_off, w_attn, W_off, 768, 192, 288, 320);
    prep_w<<<(256 * 256 + 255) / 256, 256, 0, stream>>>(w_out, nullptr, W_out, 256, 256, 256, 256);

    pad_nchw_to_nhwc<<<dim3(64, 4, 12), 256, 0, stream>>>(inflat, A_val, 256);
    pad_nchw_to_nhwc<<<dim3(64, 12, 4), 256, 0, stream>>>(query,  A_qry, 768);

    // offset+attn conv FIRST (consumes A_qry), then value conv reuses its space
    mfma_conv<768, 1><<<dim3(32, 5, 4),  256, 0, stream>>>(A_qry, W_off, b_off, b_attn, nullptr, offattn);
    mfma_conv<256, 0><<<dim3(32, 4, 12), 256, 0, stream>>>(A_val, W_val, b_value, nullptr, mask, value);

    msda_core_kernel<<<dim3(HW / 8, 4), 256, 0, stream>>>(value, offattn, refp, A_core);

    mfma_conv<256, 2><<<dim3(32, 4, 4),  256, 0, stream>>>(A_core, W_out, b_out, nullptr, nullptr, d_out);
}

// Round 5
// 745.492 us; speedup vs baseline: 4.9593x; 1.3469x over previous
//
#include <hip/hip_runtime.h>

#define HW 4096
typedef __bf16 bf16_t;
typedef _Float16 f16_t;
typedef __bf16 bf16x8 __attribute__((ext_vector_type(8)));
typedef float  f32x4  __attribute__((ext_vector_type(4)));

// ---------------------------------------------------------------------------
// Weight prep: OIHW fp32 -> [tap][co(COPAD)][ci] bf16 (co>=COTOT zero-padded).
// ---------------------------------------------------------------------------
__global__ void prep_w(const float* __restrict__ w0, const float* __restrict__ w1,
                       bf16_t* __restrict__ out, int CIN, int CO0, int COTOT, int COPAD)
{
    int idx = blockIdx.x * 256 + threadIdx.x;
    if (idx >= COPAD * CIN) return;
    int co = idx / CIN, ci = idx % CIN;
    #pragma unroll
    for (int tap = 0; tap < 9; ++tap) {
        float v = 0.f;
        if (co < CO0)        v = w0[((size_t)co * CIN + ci) * 9 + tap];
        else if (co < COTOT) v = w1[((size_t)(co - CO0) * CIN + ci) * 9 + tap];
        out[((size_t)tap * COPAD + co) * CIN + ci] = (bf16_t)v;
    }
}

// ---------------------------------------------------------------------------
// NCHW fp32 -> zero-padded (66x66) NHWC bf16. Borders pre-zeroed by memset.
// ---------------------------------------------------------------------------
__global__ __launch_bounds__(256) void pad_nchw_to_nhwc(
    const float* __restrict__ in, bf16_t* __restrict__ out, int C)
{
    const int y = blockIdx.x, ct = blockIdx.y, img = blockIdx.z;
    const int tid = threadIdx.x;
    __shared__ float t[64][65];

    int c = tid >> 2, x0 = (tid & 3) * 16;
    const float* srcc = in + ((size_t)img * C + ct * 64 + c) * HW + y * 64 + x0;
    #pragma unroll
    for (int j = 0; j < 4; ++j) {
        float4 v = *(const float4*)&srcc[j * 4];
        t[c][x0 + j * 4 + 0] = v.x; t[c][x0 + j * 4 + 1] = v.y;
        t[c][x0 + j * 4 + 2] = v.z; t[c][x0 + j * 4 + 3] = v.w;
    }
    __syncthreads();
    int x = tid >> 2, cg = (tid & 3) * 16;
    bf16_t tmp[16];
    #pragma unroll
    for (int j = 0; j < 16; ++j) tmp[j] = (bf16_t)t[cg + j][x];
    bf16_t* dst = &out[((size_t)img * 4356 + (size_t)((y + 1) * 66 + (x + 1))) * C + ct * 64 + cg];
    *(bf16x8*)dst       = *(bf16x8*)&tmp[0];
    *((bf16x8*)dst + 1) = *(bf16x8*)&tmp[8];
}

// ---------------------------------------------------------------------------
// Tap-stationary implicit-GEMM 3x3 conv via bf16 MFMA.
// Tile: 128 pixels (2 rows) x 128 cout. 4 waves (2 pix-halves x 2 co-halves);
// per wave 64 pix x 64 co = acc[4][4] f32x4.
// Per ci-chunk (64 ci): stage A-patch [4 rows][66 cols][64 ci] in LDS ONCE,
// then loop 9 taps reading shifted windows from LDS (ci-contiguous => aligned),
// B tile [128co][64ci] per tap, register-prefetched + LDS double-buffered.
// XOR swizzle q^=(col&7) / q^=(r&7) on write AND read (same involution).
// MODE 0: -> value NHWC bf16 [img][4096][256], +bias, *!mask
// MODE 1: -> offattn f16 [n][4096][288] (co<192 bias0, else bias1; COPAD=384)
// MODE 2: swapped operands -> d_out NCHW f32 (+bias), coalesced stores
// ---------------------------------------------------------------------------
template<int CIN, int MODE>
__global__ __launch_bounds__(256) void mfma_conv(
    const bf16_t* __restrict__ Apad,   // [img][66*66][CIN]
    const bf16_t* __restrict__ Wprep,  // [9][COPAD][CIN]
    const float* __restrict__ bias0,
    const float* __restrict__ bias1,
    const unsigned char* __restrict__ mask,
    void* __restrict__ outp)
{
    constexpr int NCHUNK = CIN / 64;
    constexpr int COPAD = (MODE == 1) ? 384 : 256;

    const int bx = blockIdx.x;   // pixel tile (2 output rows)
    const int by = blockIdx.y;   // co tile (128 co)
    const int img = blockIdx.z;

    const int tid = threadIdx.x;
    const int l = tid & 63;
    const int w = tid >> 6;
    const int wm = w >> 1, wn = w & 1;   // pixel-half, co-half
    const int y0 = bx * 2;
    const int cobase = by * 128;

    __shared__ bf16_t ldsA[4 * 66 * 64];     // 33.8 KB
    __shared__ bf16_t ldsB[2][128 * 64];     // 32 KB

    const bf16_t* Aimg = Apad + (size_t)img * (66 * 66) * CIN;

    f32x4 acc[4][4];
    #pragma unroll
    for (int m = 0; m < 4; ++m)
        #pragma unroll
        for (int n = 0; n < 4; ++n) acc[m][n] = (f32x4){0.f, 0.f, 0.f, 0.f};

    float4 rB[4];
    auto loadB = [&](int tap, int ci0) {
        #pragma unroll
        for (int k = 0; k < 4; ++k) {
            int s = k * 256 + tid;
            int r = s >> 3, q = s & 7;
            rB[k] = *(const float4*)(Wprep + ((size_t)tap * COPAD + cobase + r) * CIN + ci0 + q * 8);
        }
    };
    auto writeB = [&](int buf) {
        #pragma unroll
        for (int k = 0; k < 4; ++k) {
            int s = k * 256 + tid;
            int r = s >> 3, q = s & 7;
            *(float4*)&ldsB[buf][r * 64 + ((q ^ (r & 7)) * 8)] = rB[k];
        }
    };

    auto rdA = [&](int dy, int dx, int m, int kk) -> bf16x8 {
        int col = m * 16 + (l & 15) + dx;
        int kq = kk * 4 + (l >> 4);
        float4 v = *(const float4*)&ldsA[((wm + dy) * 66 + col) * 64 + ((kq ^ (col & 7)) * 8)];
        return __builtin_bit_cast(bf16x8, v);
    };
    auto rdB = [&](int buf, int n, int kk) -> bf16x8 {
        int r = wn * 64 + n * 16 + (l & 15);
        int kq = kk * 4 + (l >> 4);
        float4 v = *(const float4*)&ldsB[buf][r * 64 + ((kq ^ (r & 7)) * 8)];
        return __builtin_bit_cast(bf16x8, v);
    };

    for (int chunk = 0; chunk < NCHUNK; ++chunk) {
        const int ci0 = chunk * 64;
        // ---- stage A-patch: 4 rows x 66 cols x 64 ci (2112 16B-chunks) ----
        float4 tmpA[9];
        int arow[9], acol[9], aq[9];
        #pragma unroll
        for (int k = 0; k < 9; ++k) {
            int c = k * 256 + tid;
            if (c < 2112) {
                arow[k] = c / 528;
                int rem = c % 528;
                acol[k] = rem >> 3;
                aq[k]   = rem & 7;
                tmpA[k] = *(const float4*)(Aimg + ((size_t)(y0 + arow[k]) * 66 + acol[k]) * CIN + ci0 + aq[k] * 8);
            }
        }
        loadB(0, ci0);
        #pragma unroll
        for (int k = 0; k < 9; ++k) {
            int c = k * 256 + tid;
            if (c < 2112)
                *(float4*)&ldsA[(arow[k] * 66 + acol[k]) * 64 + ((aq[k] ^ (acol[k] & 7)) * 8)] = tmpA[k];
        }
        writeB(0);
        __syncthreads();

        int buf = 0;
        for (int tap = 0; tap < 9; ++tap) {
            const int dy = tap / 3, dx = tap % 3;
            if (tap < 8) loadB(tap + 1, ci0);   // prefetch next B (L2-resident)
            #pragma unroll
            for (int kk = 0; kk < 2; ++kk) {
                bf16x8 a0 = rdA(dy, dx, 0, kk), a1 = rdA(dy, dx, 1, kk);
                bf16x8 a2 = rdA(dy, dx, 2, kk), a3 = rdA(dy, dx, 3, kk);
                bf16x8 b0 = rdB(buf, 0, kk), b1 = rdB(buf, 1, kk);
                bf16x8 b2 = rdB(buf, 2, kk), b3 = rdB(buf, 3, kk);
                if constexpr (MODE == 2) {
                    #pragma unroll
                    for (int m = 0; m < 4; ++m) {
                        bf16x8 am = (m == 0) ? a0 : (m == 1) ? a1 : (m == 2) ? a2 : a3;
                        acc[m][0] = __builtin_amdgcn_mfma_f32_16x16x32_bf16(b0, am, acc[m][0], 0, 0, 0);
                        acc[m][1] = __builtin_amdgcn_mfma_f32_16x16x32_bf16(b1, am, acc[m][1], 0, 0, 0);
                        acc[m][2] = __builtin_amdgcn_mfma_f32_16x16x32_bf16(b2, am, acc[m][2], 0, 0, 0);
                        acc[m][3] = __builtin_amdgcn_mfma_f32_16x16x32_bf16(b3, am, acc[m][3], 0, 0, 0);
                    }
                } else {
                    #pragma unroll
                    for (int m = 0; m < 4; ++m) {
                        bf16x8 am = (m == 0) ? a0 : (m == 1) ? a1 : (m == 2) ? a2 : a3;
                        acc[m][0] = __builtin_amdgcn_mfma_f32_16x16x32_bf16(am, b0, acc[m][0], 0, 0, 0);
                        acc[m][1] = __builtin_amdgcn_mfma_f32_16x16x32_bf16(am, b1, acc[m][1], 0, 0, 0);
                        acc[m][2] = __builtin_amdgcn_mfma_f32_16x16x32_bf16(am, b2, acc[m][2], 0, 0, 0);
                        acc[m][3] = __builtin_amdgcn_mfma_f32_16x16x32_bf16(am, b3, acc[m][3], 0, 0, 0);
                    }
                }
            }
            if (tap < 8) writeB(buf ^ 1);
            __syncthreads();
            buf ^= 1;
        }
    }

    // ---- epilogue ----
    #pragma unroll
    for (int m = 0; m < 4; ++m)
        #pragma unroll
        for (int n = 0; n < 4; ++n) {
            f32x4 fr = acc[m][n];
            if constexpr (MODE == 2) {
                int co  = cobase + wn * 64 + n * 16 + (l >> 4) * 4;
                int pix = bx * 128 + wm * 64 + m * 16 + (l & 15);
                float* op = (float*)outp;
                #pragma unroll
                for (int r = 0; r < 4; ++r)
                    op[((size_t)img * 256 + co + r) * HW + pix] = fr[r] + bias0[co + r];
            } else {
                int pix = bx * 128 + wm * 64 + m * 16 + (l >> 4) * 4;
                int co  = cobase + wn * 64 + n * 16 + (l & 15);
                if constexpr (MODE == 0) {
                    bf16_t* op = (bf16_t*)outp;
                    float bv = bias0[co];
                    #pragma unroll
                    for (int r = 0; r < 4; ++r) {
                        int p = pix + r;
                        float vv = fr[r] + bv;
                        if (mask[(size_t)img * HW + p]) vv = 0.f;
                        op[((size_t)img * HW + p) * 256 + co] = (bf16_t)vv;
                    }
                } else {
                    if (co < 288) {
                        f16_t* op = (f16_t*)outp;
                        float bv = (co < 192) ? bias0[co] : bias1[co - 192];
                        #pragma unroll
                        for (int r = 0; r < 4; ++r)
                            op[((size_t)img * HW + pix + r) * 288 + co] = (f16_t)(fr[r] + bv);
                    }
                }
            }
        }
}

// ---------------------------------------------------------------------------
// Deformable sampling core. 256 threads = 256 channels, QB=8 queries.
// ---------------------------------------------------------------------------
__global__ __launch_bounds__(256) void msda_core_kernel(
    const bf16_t* __restrict__ value,
    const f16_t* __restrict__ offattn,
    const float* __restrict__ refp,
    bf16_t* __restrict__ outpad)
{
    constexpr int QB = 8;
    const int n   = blockIdx.y;
    const int q0  = blockIdx.x * QB;
    const int tid = threadIdx.x;
    const int hd  = tid >> 5;

    __shared__ float s_oa[QB][288];
    __shared__ float s_ref[QB][6];
    __shared__ float s_aw[QB][96];

    for (int e = tid; e < QB * 288; e += 256) {
        int qq = e / 288, c = e % 288;
        s_oa[qq][c] = (float)offattn[((size_t)n * HW + q0 + qq) * 288 + c];
    }
    if (tid < QB * 6) {
        int qq = tid / 6, r = tid % 6;
        s_ref[qq][r] = refp[((size_t)n * HW + q0 + qq) * 6 + r];
    }
    __syncthreads();

    if (tid < QB * 8) {
        int qq = tid >> 3, h = tid & 7;
        const float* a = &s_oa[qq][192 + h * 12];
        float mx = a[0];
        #pragma unroll
        for (int k = 1; k < 12; ++k) mx = fmaxf(mx, a[k]);
        float e[12]; float sum = 0.f;
        #pragma unroll
        for (int k = 0; k < 12; ++k) { e[k] = __expf(a[k] - mx); sum += e[k]; }
        float inv = 1.f / sum;
        #pragma unroll
        for (int k = 0; k < 12; ++k) s_aw[qq][h * 12 + k] = e[k] * inv;
    }
    __syncthreads();

    float accq[QB];
    #pragma unroll
    for (int qq = 0; qq < QB; ++qq) accq[qq] = 0.f;

    #pragma unroll
    for (int qq = 0; qq < QB; ++qq) {
        for (int ll = 0; ll < 3; ++ll) {
            const bf16_t* vbase = value + ((size_t)(n * 3 + ll) * HW) * 256 + tid;
            float rx = s_ref[qq][ll * 2 + 0] * 64.f - 0.5f;
            float ry = s_ref[qq][ll * 2 + 1] * 64.f - 0.5f;
            #pragma unroll
            for (int p = 0; p < 4; ++p) {
                int idx = hd * 12 + ll * 4 + p;
                float x = rx + s_oa[qq][idx * 2 + 0];
                float y = ry + s_oa[qq][idx * 2 + 1];
                float aw = s_aw[qq][idx];
                float xf = floorf(x), yf = floorf(y);
                float lx = x - xf, ly = y - yf;
                int xi = (int)xf, yi = (int)yf;
                float w00 = (1.f - lx) * (1.f - ly) * aw;
                float w10 = lx * (1.f - ly) * aw;
                float w01 = (1.f - lx) * ly * aw;
                float w11 = lx * ly * aw;
                bool vx0 = (xi >= 0) && (xi < 64);
                bool vx1 = (xi + 1 >= 0) && (xi + 1 < 64);
                if (yi >= 0 && yi < 64) {
                    int row = yi * 64;
                    if (vx0) accq[qq] = fmaf(w00, (float)vbase[(size_t)(row + xi) * 256], accq[qq]);
                    if (vx1) accq[qq] = fmaf(w10, (float)vbase[(size_t)(row + xi + 1) * 256], accq[qq]);
                }
                if (yi + 1 >= 0 && yi + 1 < 64) {
                    int row = (yi + 1) * 64;
                    if (vx0) accq[qq] = fmaf(w01, (float)vbase[(size_t)(row + xi) * 256], accq[qq]);
                    if (vx1) accq[qq] = fmaf(w11, (float)vbase[(size_t)(row + xi + 1) * 256], accq[qq]);
                }
            }
        }
    }

    #pragma unroll
    for (int qq = 0; qq < QB; ++qq) {
        int pix = q0 + qq;
        int pp = ((pix >> 6) + 1) * 66 + (pix & 63) + 1;
        outpad[((size_t)n * 4356 + pp) * 256 + tid] = (bf16_t)accq[qq];
    }
}

extern "C" void kernel_launch(void* const* d_in, const int* in_sizes, int n_in,
                              void* d_out, int out_size, void* d_ws, size_t ws_size,
                              hipStream_t stream) {
    const float* query   = (const float*)d_in[0];
    const float* refp    = (const float*)d_in[1];
    const float* inflat  = (const float*)d_in[2];
    const unsigned char* mask = (const unsigned char*)d_in[5];
    const float* w_value = (const float*)d_in[6];
    const float* b_value = (const float*)d_in[7];
    const float* w_off   = (const float*)d_in[8];
    const float* b_off   = (const float*)d_in[9];
    const float* w_attn  = (const float*)d_in[10];
    const float* b_attn  = (const float*)d_in[11];
    const float* w_out   = (const float*)d_in[12];
    const float* b_out   = (const float*)d_in[13];

    char* ws = (char*)d_ws;
    bf16_t* A_val  = (bf16_t*)ws;  ws += (size_t)12 * 4356 * 256 * 2;  // 26.76 MB
    bf16_t* A_qry  = (bf16_t*)ws;  ws += (size_t)4 * 4356 * 768 * 2;   // 26.76 MB
    bf16_t* A_core = (bf16_t*)ws;  ws += (size_t)4 * 4356 * 256 * 2;   // 8.92 MB
    size_t pad_bytes = (size_t)(12 * 4356 * 256 + 4 * 4356 * 768 + 4 * 4356 * 256) * 2;
    bf16_t* W_val  = (bf16_t*)ws;  ws += (size_t)9 * 256 * 256 * 2;
    bf16_t* W_off  = (bf16_t*)ws;  ws += (size_t)9 * 384 * 768 * 2;    // COPAD=384
    bf16_t* W_out  = (bf16_t*)ws;  ws += (size_t)9 * 256 * 256 * 2;
    f16_t*  offattn = (f16_t*)ws;  ws += (size_t)4 * 4096 * 288 * 2;   // 9.44 MB
    bf16_t* value  = A_qry;  // reuse: off-conv consumes A_qry before value conv writes
    // total ws ~ 80.5 MiB (< 86 MiB proven available by round 1)

    hipMemsetAsync(d_ws, 0, pad_bytes, stream);

    prep_w<<<(256 * 256 + 255) / 256, 256, 0, stream>>>(w_value, nullptr, W_val, 256, 256, 256, 256);
    prep_w<<<(384 * 768 + 255) / 256, 256, 0, stream>>>(w_off, w_attn, W_off, 768, 192, 288, 384);
    prep_w<<<(256 * 256 + 255) / 256, 256, 0, stream>>>(w_out, nullptr, W_out, 256, 256, 256, 256);

    pad_nchw_to_nhwc<<<dim3(64, 4, 12), 256, 0, stream>>>(inflat, A_val, 256);
    pad_nchw_to_nhwc<<<dim3(64, 12, 4), 256, 0, stream>>>(query,  A_qry, 768);

    mfma_conv<768, 1><<<dim3(32, 3, 4),  256, 0, stream>>>(A_qry, W_off, b_off, b_attn, nullptr, offattn);
    mfma_conv<256, 0><<<dim3(32, 2, 12), 256, 0, stream>>>(A_val, W_val, b_value, nullptr, mask, value);

    msda_core_kernel<<<dim3(HW / 8, 4), 256, 0, stream>>>(value, offattn, refp, A_core);

    mfma_conv<256, 2><<<dim3(32, 2, 4),  256, 0, stream>>>(A_core, W_out, b_out, nullptr, nullptr, d_out);
}

// Round 6
// 387.917 us; speedup vs baseline: 9.5307x; 1.9218x over previous
//
#include <hip/hip_runtime.h>

#define HW 4096
typedef __bf16 bf16_t;
typedef _Float16 f16_t;
typedef __bf16 bf16x8 __attribute__((ext_vector_type(8)));
typedef float  f32x4  __attribute__((ext_vector_type(4)));
typedef unsigned int u32;

__device__ __forceinline__ void gld_lds16(const void* g, void* l) {
    __builtin_amdgcn_global_load_lds(
        (const __attribute__((address_space(1))) u32*)g,
        (__attribute__((address_space(3))) u32*)l, 16, 0, 0);
}

// ---------------------------------------------------------------------------
// Weight prep: OIHW fp32 -> [tap][co(COPAD)][ci] bf16 (co>=COTOT zero-padded).
// ---------------------------------------------------------------------------
__global__ void prep_w(const float* __restrict__ w0, const float* __restrict__ w1,
                       bf16_t* __restrict__ out, int CIN, int CO0, int COTOT, int COPAD)
{
    int idx = blockIdx.x * 256 + threadIdx.x;
    if (idx >= COPAD * CIN) return;
    int co = idx / CIN, ci = idx % CIN;
    #pragma unroll
    for (int tap = 0; tap < 9; ++tap) {
        float v = 0.f;
        if (co < CO0)        v = w0[((size_t)co * CIN + ci) * 9 + tap];
        else if (co < COTOT) v = w1[((size_t)(co - CO0) * CIN + ci) * 9 + tap];
        out[((size_t)tap * COPAD + co) * CIN + ci] = (bf16_t)v;
    }
}

// ---------------------------------------------------------------------------
// NCHW fp32 -> zero-padded (66x66) NHWC bf16. Borders pre-zeroed by memset.
// ---------------------------------------------------------------------------
__global__ __launch_bounds__(256) void pad_nchw_to_nhwc(
    const float* __restrict__ in, bf16_t* __restrict__ out, int C)
{
    const int y = blockIdx.x, ct = blockIdx.y, img = blockIdx.z;
    const int tid = threadIdx.x;
    __shared__ float t[64][65];

    int c = tid >> 2, x0 = (tid & 3) * 16;
    const float* srcc = in + ((size_t)img * C + ct * 64 + c) * HW + y * 64 + x0;
    #pragma unroll
    for (int j = 0; j < 4; ++j) {
        float4 v = *(const float4*)&srcc[j * 4];
        t[c][x0 + j * 4 + 0] = v.x; t[c][x0 + j * 4 + 1] = v.y;
        t[c][x0 + j * 4 + 2] = v.z; t[c][x0 + j * 4 + 3] = v.w;
    }
    __syncthreads();
    int x = tid >> 2, cg = (tid & 3) * 16;
    bf16_t tmp[16];
    #pragma unroll
    for (int j = 0; j < 16; ++j) tmp[j] = (bf16_t)t[cg + j][x];
    bf16_t* dst = &out[((size_t)img * 4356 + (size_t)((y + 1) * 66 + (x + 1))) * C + ct * 64 + cg];
    *(bf16x8*)dst       = *(bf16x8*)&tmp[0];
    *((bf16x8*)dst + 1) = *(bf16x8*)&tmp[8];
}

// ---------------------------------------------------------------------------
// Tap-stationary implicit-GEMM 3x3 conv, bf16 MFMA, async global_load_lds.
// Tile: 128 pixels (2 rows) x 128 cout, 4 waves (2 pix x 2 co), acc[4][4].
// Per ci-chunk (64 ci): A-patch [4 rows][66 cols][64 ci] staged ONCE by DMA;
// 9 taps read shifted windows. B [128co][64ci] per tap, DMA double-buffered:
// issue B(tap+1) -> compute(tap) -> barrier (drain). XOR involution q^=(p&7)
// applied on DMA *source* address (LDS dest linear) and on LDS read.
// MODE 0: -> value NHWC bf16 [img][4096][256], +bias, *!mask
// MODE 1: -> offattn f16 [n][4096][288] (co<192 bias0, else bias1; COPAD=384)
// MODE 2: swapped operands -> d_out NCHW f32 (+bias), coalesced stores
// ---------------------------------------------------------------------------
template<int CIN, int MODE>
__global__ __launch_bounds__(256) void mfma_conv(
    const bf16_t* __restrict__ Apad,   // [img][66*66][CIN]
    const bf16_t* __restrict__ Wprep,  // [9][COPAD][CIN]
    const float* __restrict__ bias0,
    const float* __restrict__ bias1,
    const unsigned char* __restrict__ mask,
    void* __restrict__ outp)
{
    constexpr int NCHUNK = CIN / 64;
    constexpr int COPAD = (MODE == 1) ? 384 : 256;

    // bijective XCD-chunked block swizzle (nwg % 8 == 0 for all grids)
    const int gy = gridDim.y;
    const int nwg = 32 * gy * gridDim.z;
    const int pb = blockIdx.x + 32 * (blockIdx.y + gy * blockIdx.z);
    const int lb = (pb & 7) * (nwg >> 3) + (pb >> 3);
    const int bx  = lb & 31;
    const int by  = (lb >> 5) % gy;
    const int img = lb / (32 * gy);

    const int tid = threadIdx.x;
    const int l = tid & 63;
    const int w = tid >> 6;
    const int wm = w >> 1, wn = w & 1;   // pixel-half, co-half
    const int y0 = bx * 2;
    const int cobase = by * 128;

    __shared__ bf16_t ldsA[4 * 66 * 64];     // 33.8 KB
    __shared__ bf16_t ldsB[2][128 * 64];     // 32 KB

    const bf16_t* Aimg = Apad + (size_t)img * (66 * 66) * CIN;

    f32x4 acc[4][4];
    #pragma unroll
    for (int m = 0; m < 4; ++m)
        #pragma unroll
        for (int n = 0; n < 4; ++n) acc[m][n] = (f32x4){0.f, 0.f, 0.f, 0.f};

    // A-patch DMA: 2112 16B-quads; slot s holds source quad (row,col,qs^(col&7))
    auto stageA = [&](int ci0) {
        for (int i = w; i < 33; i += 4) {
            int s = i * 64 + l;
            int row = s / 528;
            int rem = s - row * 528;
            int col = rem >> 3, qs = rem & 7;
            int qsrc = qs ^ (col & 7);
            const bf16_t* src = Aimg + ((size_t)((y0 + row) * 66 + col)) * CIN + ci0 + qsrc * 8;
            gld_lds16(src, &ldsA[i * 512]);
        }
    };
    // B-tile DMA: 1024 quads; slot s holds source quad (r, qs^(r&7))
    auto stageB = [&](int tap, int ci0, int bufsel) {
        #pragma unroll
        for (int i = 0; i < 4; ++i) {
            int s = (w * 4 + i) * 64 + l;
            int r = s >> 3, qs = s & 7;
            int qsrc = qs ^ (r & 7);
            const bf16_t* src = Wprep + ((size_t)tap * COPAD + cobase + r) * CIN + ci0 + qsrc * 8;
            gld_lds16(src, &ldsB[bufsel][(w * 4 + i) * 512]);
        }
    };

    auto rdA = [&](int dy, int dx, int m, int kk) -> bf16x8 {
        int col = m * 16 + (l & 15) + dx;
        int kq = kk * 4 + (l >> 4);
        float4 v = *(const float4*)&ldsA[((wm + dy) * 66 + col) * 64 + ((kq ^ (col & 7)) * 8)];
        return __builtin_bit_cast(bf16x8, v);
    };
    auto rdB = [&](int bufsel, int n, int kk) -> bf16x8 {
        int r = wn * 64 + n * 16 + (l & 15);
        int kq = kk * 4 + (l >> 4);
        float4 v = *(const float4*)&ldsB[bufsel][r * 64 + ((kq ^ (r & 7)) * 8)];
        return __builtin_bit_cast(bf16x8, v);
    };

    for (int chunk = 0; chunk < NCHUNK; ++chunk) {
        const int ci0 = chunk * 64;
        stageA(ci0);
        stageB(0, ci0, 0);
        __syncthreads();   // drains all DMA

        int buf = 0;
        for (int tap = 0; tap < 9; ++tap) {
            const int dy = tap / 3, dx = tap % 3;
            if (tap < 8) stageB(tap + 1, ci0, buf ^ 1);   // async DMA overlaps compute
            #pragma unroll
            for (int kk = 0; kk < 2; ++kk) {
                bf16x8 a0 = rdA(dy, dx, 0, kk), a1 = rdA(dy, dx, 1, kk);
                bf16x8 a2 = rdA(dy, dx, 2, kk), a3 = rdA(dy, dx, 3, kk);
                bf16x8 b0 = rdB(buf, 0, kk), b1 = rdB(buf, 1, kk);
                bf16x8 b2 = rdB(buf, 2, kk), b3 = rdB(buf, 3, kk);
                #pragma unroll
                for (int m = 0; m < 4; ++m) {
                    bf16x8 am = (m == 0) ? a0 : (m == 1) ? a1 : (m == 2) ? a2 : a3;
                    if constexpr (MODE == 2) {
                        acc[m][0] = __builtin_amdgcn_mfma_f32_16x16x32_bf16(b0, am, acc[m][0], 0, 0, 0);
                        acc[m][1] = __builtin_amdgcn_mfma_f32_16x16x32_bf16(b1, am, acc[m][1], 0, 0, 0);
                        acc[m][2] = __builtin_amdgcn_mfma_f32_16x16x32_bf16(b2, am, acc[m][2], 0, 0, 0);
                        acc[m][3] = __builtin_amdgcn_mfma_f32_16x16x32_bf16(b3, am, acc[m][3], 0, 0, 0);
                    } else {
                        acc[m][0] = __builtin_amdgcn_mfma_f32_16x16x32_bf16(am, b0, acc[m][0], 0, 0, 0);
                        acc[m][1] = __builtin_amdgcn_mfma_f32_16x16x32_bf16(am, b1, acc[m][1], 0, 0, 0);
                        acc[m][2] = __builtin_amdgcn_mfma_f32_16x16x32_bf16(am, b2, acc[m][2], 0, 0, 0);
                        acc[m][3] = __builtin_amdgcn_mfma_f32_16x16x32_bf16(am, b3, acc[m][3], 0, 0, 0);
                    }
                }
            }
            __syncthreads();   // drains B(tap+1) DMA + all reads of buf
            buf ^= 1;
        }
    }

    // ---- epilogue ----
    #pragma unroll
    for (int m = 0; m < 4; ++m)
        #pragma unroll
        for (int n = 0; n < 4; ++n) {
            f32x4 fr = acc[m][n];
            if constexpr (MODE == 2) {
                int co  = cobase + wn * 64 + n * 16 + (l >> 4) * 4;
                int pix = bx * 128 + wm * 64 + m * 16 + (l & 15);
                float* op = (float*)outp;
                #pragma unroll
                for (int r = 0; r < 4; ++r)
                    op[((size_t)img * 256 + co + r) * HW + pix] = fr[r] + bias0[co + r];
            } else {
                int pix = bx * 128 + wm * 64 + m * 16 + (l >> 4) * 4;
                int co  = cobase + wn * 64 + n * 16 + (l & 15);
                if constexpr (MODE == 0) {
                    bf16_t* op = (bf16_t*)outp;
                    float bv = bias0[co];
                    #pragma unroll
                    for (int r = 0; r < 4; ++r) {
                        int p = pix + r;
                        float vv = fr[r] + bv;
                        if (mask[(size_t)img * HW + p]) vv = 0.f;
                        op[((size_t)img * HW + p) * 256 + co] = (bf16_t)vv;
                    }
                } else {
                    if (co < 288) {
                        f16_t* op = (f16_t*)outp;
                        float bv = (co < 192) ? bias0[co] : bias1[co - 192];
                        #pragma unroll
                        for (int r = 0; r < 4; ++r)
                            op[((size_t)img * HW + pix + r) * 288 + co] = (f16_t)(fr[r] + bv);
                    }
                }
            }
        }
}

// ---------------------------------------------------------------------------
// Deformable sampling core. 256 threads = 256 channels, QB=8 queries.
// ---------------------------------------------------------------------------
__global__ __launch_bounds__(256) void msda_core_kernel(
    const bf16_t* __restrict__ value,
    const f16_t* __restrict__ offattn,
    const float* __restrict__ refp,
    bf16_t* __restrict__ outpad)
{
    constexpr int QB = 8;
    const int n   = blockIdx.y;
    const int q0  = blockIdx.x * QB;
    const int tid = threadIdx.x;
    const int hd  = tid >> 5;

    __shared__ float s_oa[QB][288];
    __shared__ float s_ref[QB][6];
    __shared__ float s_aw[QB][96];

    for (int e = tid; e < QB * 288; e += 256) {
        int qq = e / 288, c = e % 288;
        s_oa[qq][c] = (float)offattn[((size_t)n * HW + q0 + qq) * 288 + c];
    }
    if (tid < QB * 6) {
        int qq = tid / 6, r = tid % 6;
        s_ref[qq][r] = refp[((size_t)n * HW + q0 + qq) * 6 + r];
    }
    __syncthreads();

    if (tid < QB * 8) {
        int qq = tid >> 3, h = tid & 7;
        const float* a = &s_oa[qq][192 + h * 12];
        float mx = a[0];
        #pragma unroll
        for (int k = 1; k < 12; ++k) mx = fmaxf(mx, a[k]);
        float e[12]; float sum = 0.f;
        #pragma unroll
        for (int k = 0; k < 12; ++k) { e[k] = __expf(a[k] - mx); sum += e[k]; }
        float inv = 1.f / sum;
        #pragma unroll
        for (int k = 0; k < 12; ++k) s_aw[qq][h * 12 + k] = e[k] * inv;
    }
    __syncthreads();

    float accq[QB];
    #pragma unroll
    for (int qq = 0; qq < QB; ++qq) accq[qq] = 0.f;

    #pragma unroll
    for (int qq = 0; qq < QB; ++qq) {
        for (int ll = 0; ll < 3; ++ll) {
            const bf16_t* vbase = value + ((size_t)(n * 3 + ll) * HW) * 256 + tid;
            float rx = s_ref[qq][ll * 2 + 0] * 64.f - 0.5f;
            float ry = s_ref[qq][ll * 2 + 1] * 64.f - 0.5f;
            #pragma unroll
            for (int p = 0; p < 4; ++p) {
                int idx = hd * 12 + ll * 4 + p;
                float x = rx + s_oa[qq][idx * 2 + 0];
                float y = ry + s_oa[qq][idx * 2 + 1];
                float aw = s_aw[qq][idx];
                float xf = floorf(x), yf = floorf(y);
                float lx = x - xf, ly = y - yf;
                int xi = (int)xf, yi = (int)yf;
                float w00 = (1.f - lx) * (1.f - ly) * aw;
                float w10 = lx * (1.f - ly) * aw;
                float w01 = (1.f - lx) * ly * aw;
                float w11 = lx * ly * aw;
                bool vx0 = (xi >= 0) && (xi < 64);
                bool vx1 = (xi + 1 >= 0) && (xi + 1 < 64);
                if (yi >= 0 && yi < 64) {
                    int row = yi * 64;
                    if (vx0) accq[qq] = fmaf(w00, (float)vbase[(size_t)(row + xi) * 256], accq[qq]);
                    if (vx1) accq[qq] = fmaf(w10, (float)vbase[(size_t)(row + xi + 1) * 256], accq[qq]);
                }
                if (yi + 1 >= 0 && yi + 1 < 64) {
                    int row = (yi + 1) * 64;
                    if (vx0) accq[qq] = fmaf(w01, (float)vbase[(size_t)(row + xi) * 256], accq[qq]);
                    if (vx1) accq[qq] = fmaf(w11, (float)vbase[(size_t)(row + xi + 1) * 256], accq[qq]);
                }
            }
        }
    }

    #pragma unroll
    for (int qq = 0; qq < QB; ++qq) {
        int pix = q0 + qq;
        int pp = ((pix >> 6) + 1) * 66 + (pix & 63) + 1;
        outpad[((size_t)n * 4356 + pp) * 256 + tid] = (bf16_t)accq[qq];
    }
}

extern "C" void kernel_launch(void* const* d_in, const int* in_sizes, int n_in,
                              void* d_out, int out_size, void* d_ws, size_t ws_size,
                              hipStream_t stream) {
    const float* query   = (const float*)d_in[0];
    const float* refp    = (const float*)d_in[1];
    const float* inflat  = (const float*)d_in[2];
    const unsigned char* mask = (const unsigned char*)d_in[5];
    const float* w_value = (const float*)d_in[6];
    const float* b_value = (const float*)d_in[7];
    const float* w_off   = (const float*)d_in[8];
    const float* b_off   = (const float*)d_in[9];
    const float* w_attn  = (const float*)d_in[10];
    const float* b_attn  = (const float*)d_in[11];
    const float* w_out   = (const float*)d_in[12];
    const float* b_out   = (const float*)d_in[13];

    char* ws = (char*)d_ws;
    bf16_t* A_val  = (bf16_t*)ws;  ws += (size_t)12 * 4356 * 256 * 2;  // 26.76 MB
    bf16_t* A_qry  = (bf16_t*)ws;  ws += (size_t)4 * 4356 * 768 * 2;   // 26.76 MB
    bf16_t* A_core = (bf16_t*)ws;  ws += (size_t)4 * 4356 * 256 * 2;   // 8.92 MB
    size_t pad_bytes = (size_t)(12 * 4356 * 256 + 4 * 4356 * 768 + 4 * 4356 * 256) * 2;
    bf16_t* W_val  = (bf16_t*)ws;  ws += (size_t)9 * 256 * 256 * 2;
    bf16_t* W_off  = (bf16_t*)ws;  ws += (size_t)9 * 384 * 768 * 2;    // COPAD=384
    bf16_t* W_out  = (bf16_t*)ws;  ws += (size_t)9 * 256 * 256 * 2;
    f16_t*  offattn = (f16_t*)ws;  ws += (size_t)4 * 4096 * 288 * 2;   // 9.44 MB
    bf16_t* value  = A_qry;  // reuse: off-conv consumes A_qry before value conv writes
    // total ws ~ 80.5 MiB (< 86 MiB proven available by round 1)

    hipMemsetAsync(d_ws, 0, pad_bytes, stream);

    prep_w<<<(256 * 256 + 255) / 256, 256, 0, stream>>>(w_value, nullptr, W_val, 256, 256, 256, 256);
    prep_w<<<(384 * 768 + 255) / 256, 256, 0, stream>>>(w_off, w_attn, W_off, 768, 192, 288, 384);
    prep_w<<<(256 * 256 + 255) / 256, 256, 0, stream>>>(w_out, nullptr, W_out, 256, 256, 256, 256);

    pad_nchw_to_nhwc<<<dim3(64, 4, 12), 256, 0, stream>>>(inflat, A_val, 256);
    pad_nchw_to_nhwc<<<dim3(64, 12, 4), 256, 0, stream>>>(query,  A_qry, 768);

    mfma_conv<768, 1><<<dim3(32, 3, 4),  256, 0, stream>>>(A_qry, W_off, b_off, b_attn, nullptr, offattn);
    mfma_conv<256, 0><<<dim3(32, 2, 12), 256, 0, stream>>>(A_val, W_val, b_value, nullptr, mask, value);

    msda_core_kernel<<<dim3(HW / 8, 4), 256, 0, stream>>>(value, offattn, refp, A_core);

    mfma_conv<256, 2><<<dim3(32, 2, 4),  256, 0, stream>>>(A_core, W_out, b_out, nullptr, nullptr, d_out);
}

// Round 7
// 361.734 us; speedup vs baseline: 10.2205x; 1.0724x over previous
//
#include <hip/hip_runtime.h>

#define HW 4096
typedef __bf16 bf16_t;
typedef _Float16 f16_t;
typedef __bf16 bf16x8 __attribute__((ext_vector_type(8)));
typedef float  f32x4  __attribute__((ext_vector_type(4)));
typedef unsigned int u32;

__device__ __forceinline__ void gld_lds16(const void* g, void* l) {
    __builtin_amdgcn_global_load_lds(
        (const __attribute__((address_space(1))) u32*)g,
        (__attribute__((address_space(3))) u32*)l, 16, 0, 0);
}

// ---------------------------------------------------------------------------
// Weight prep: OIHW fp32 -> [tap][co(COPAD)][ci] bf16 (co>=COTOT zero-padded).
// ---------------------------------------------------------------------------
__global__ void prep_w(const float* __restrict__ w0, const float* __restrict__ w1,
                       bf16_t* __restrict__ out, int CIN, int CO0, int COTOT, int COPAD)
{
    int idx = blockIdx.x * 256 + threadIdx.x;
    if (idx >= COPAD * CIN) return;
    int co = idx / CIN, ci = idx % CIN;
    #pragma unroll
    for (int tap = 0; tap < 9; ++tap) {
        float v = 0.f;
        if (co < CO0)        v = w0[((size_t)co * CIN + ci) * 9 + tap];
        else if (co < COTOT) v = w1[((size_t)(co - CO0) * CIN + ci) * 9 + tap];
        out[((size_t)tap * COPAD + co) * CIN + ci] = (bf16_t)v;
    }
}

// ---------------------------------------------------------------------------
// NCHW fp32 -> zero-padded (66x66) NHWC bf16. Borders pre-zeroed by memset.
// ---------------------------------------------------------------------------
__global__ __launch_bounds__(256) void pad_nchw_to_nhwc(
    const float* __restrict__ in, bf16_t* __restrict__ out, int C)
{
    const int y = blockIdx.x, ct = blockIdx.y, img = blockIdx.z;
    const int tid = threadIdx.x;
    __shared__ float t[64][65];

    int c = tid >> 2, x0 = (tid & 3) * 16;
    const float* srcc = in + ((size_t)img * C + ct * 64 + c) * HW + y * 64 + x0;
    #pragma unroll
    for (int j = 0; j < 4; ++j) {
        float4 v = *(const float4*)&srcc[j * 4];
        t[c][x0 + j * 4 + 0] = v.x; t[c][x0 + j * 4 + 1] = v.y;
        t[c][x0 + j * 4 + 2] = v.z; t[c][x0 + j * 4 + 3] = v.w;
    }
    __syncthreads();
    int x = tid >> 2, cg = (tid & 3) * 16;
    bf16_t tmp[16];
    #pragma unroll
    for (int j = 0; j < 16; ++j) tmp[j] = (bf16_t)t[cg + j][x];
    bf16_t* dst = &out[((size_t)img * 4356 + (size_t)((y + 1) * 66 + (x + 1))) * C + ct * 64 + cg];
    *(bf16x8*)dst       = *(bf16x8*)&tmp[0];
    *((bf16x8*)dst + 1) = *(bf16x8*)&tmp[8];
}

// ---------------------------------------------------------------------------
// Tap-stationary implicit-GEMM 3x3 conv, bf16 MFMA, async global_load_lds.
// (unchanged from R6 — see comments there)
// ---------------------------------------------------------------------------
template<int CIN, int MODE>
__global__ __launch_bounds__(256) void mfma_conv(
    const bf16_t* __restrict__ Apad,   // [img][66*66][CIN]
    const bf16_t* __restrict__ Wprep,  // [9][COPAD][CIN]
    const float* __restrict__ bias0,
    const float* __restrict__ bias1,
    const unsigned char* __restrict__ mask,
    void* __restrict__ outp)
{
    constexpr int NCHUNK = CIN / 64;
    constexpr int COPAD = (MODE == 1) ? 384 : 256;

    const int gy = gridDim.y;
    const int nwg = 32 * gy * gridDim.z;
    const int pb = blockIdx.x + 32 * (blockIdx.y + gy * blockIdx.z);
    const int lb = (pb & 7) * (nwg >> 3) + (pb >> 3);
    const int bx  = lb & 31;
    const int by  = (lb >> 5) % gy;
    const int img = lb / (32 * gy);

    const int tid = threadIdx.x;
    const int l = tid & 63;
    const int w = tid >> 6;
    const int wm = w >> 1, wn = w & 1;
    const int y0 = bx * 2;
    const int cobase = by * 128;

    __shared__ bf16_t ldsA[4 * 66 * 64];
    __shared__ bf16_t ldsB[2][128 * 64];

    const bf16_t* Aimg = Apad + (size_t)img * (66 * 66) * CIN;

    f32x4 acc[4][4];
    #pragma unroll
    for (int m = 0; m < 4; ++m)
        #pragma unroll
        for (int n = 0; n < 4; ++n) acc[m][n] = (f32x4){0.f, 0.f, 0.f, 0.f};

    auto stageA = [&](int ci0) {
        for (int i = w; i < 33; i += 4) {
            int s = i * 64 + l;
            int row = s / 528;
            int rem = s - row * 528;
            int col = rem >> 3, qs = rem & 7;
            int qsrc = qs ^ (col & 7);
            const bf16_t* src = Aimg + ((size_t)((y0 + row) * 66 + col)) * CIN + ci0 + qsrc * 8;
            gld_lds16(src, &ldsA[i * 512]);
        }
    };
    auto stageB = [&](int tap, int ci0, int bufsel) {
        #pragma unroll
        for (int i = 0; i < 4; ++i) {
            int s = (w * 4 + i) * 64 + l;
            int r = s >> 3, qs = s & 7;
            int qsrc = qs ^ (r & 7);
            const bf16_t* src = Wprep + ((size_t)tap * COPAD + cobase + r) * CIN + ci0 + qsrc * 8;
            gld_lds16(src, &ldsB[bufsel][(w * 4 + i) * 512]);
        }
    };

    auto rdA = [&](int dy, int dx, int m, int kk) -> bf16x8 {
        int col = m * 16 + (l & 15) + dx;
        int kq = kk * 4 + (l >> 4);
        float4 v = *(const float4*)&ldsA[((wm + dy) * 66 + col) * 64 + ((kq ^ (col & 7)) * 8)];
        return __builtin_bit_cast(bf16x8, v);
    };
    auto rdB = [&](int bufsel, int n, int kk) -> bf16x8 {
        int r = wn * 64 + n * 16 + (l & 15);
        int kq = kk * 4 + (l >> 4);
        float4 v = *(const float4*)&ldsB[bufsel][r * 64 + ((kq ^ (r & 7)) * 8)];
        return __builtin_bit_cast(bf16x8, v);
    };

    for (int chunk = 0; chunk < NCHUNK; ++chunk) {
        const int ci0 = chunk * 64;
        stageA(ci0);
        stageB(0, ci0, 0);
        __syncthreads();

        int buf = 0;
        for (int tap = 0; tap < 9; ++tap) {
            const int dy = tap / 3, dx = tap % 3;
            if (tap < 8) stageB(tap + 1, ci0, buf ^ 1);
            #pragma unroll
            for (int kk = 0; kk < 2; ++kk) {
                bf16x8 a0 = rdA(dy, dx, 0, kk), a1 = rdA(dy, dx, 1, kk);
                bf16x8 a2 = rdA(dy, dx, 2, kk), a3 = rdA(dy, dx, 3, kk);
                bf16x8 b0 = rdB(buf, 0, kk), b1 = rdB(buf, 1, kk);
                bf16x8 b2 = rdB(buf, 2, kk), b3 = rdB(buf, 3, kk);
                #pragma unroll
                for (int m = 0; m < 4; ++m) {
                    bf16x8 am = (m == 0) ? a0 : (m == 1) ? a1 : (m == 2) ? a2 : a3;
                    if constexpr (MODE == 2) {
                        acc[m][0] = __builtin_amdgcn_mfma_f32_16x16x32_bf16(b0, am, acc[m][0], 0, 0, 0);
                        acc[m][1] = __builtin_amdgcn_mfma_f32_16x16x32_bf16(b1, am, acc[m][1], 0, 0, 0);
                        acc[m][2] = __builtin_amdgcn_mfma_f32_16x16x32_bf16(b2, am, acc[m][2], 0, 0, 0);
                        acc[m][3] = __builtin_amdgcn_mfma_f32_16x16x32_bf16(b3, am, acc[m][3], 0, 0, 0);
                    } else {
                        acc[m][0] = __builtin_amdgcn_mfma_f32_16x16x32_bf16(am, b0, acc[m][0], 0, 0, 0);
                        acc[m][1] = __builtin_amdgcn_mfma_f32_16x16x32_bf16(am, b1, acc[m][1], 0, 0, 0);
                        acc[m][2] = __builtin_amdgcn_mfma_f32_16x16x32_bf16(am, b2, acc[m][2], 0, 0, 0);
                        acc[m][3] = __builtin_amdgcn_mfma_f32_16x16x32_bf16(am, b3, acc[m][3], 0, 0, 0);
                    }
                }
            }
            __syncthreads();
            buf ^= 1;
        }
    }

    #pragma unroll
    for (int m = 0; m < 4; ++m)
        #pragma unroll
        for (int n = 0; n < 4; ++n) {
            f32x4 fr = acc[m][n];
            if constexpr (MODE == 2) {
                int co  = cobase + wn * 64 + n * 16 + (l >> 4) * 4;
                int pix = bx * 128 + wm * 64 + m * 16 + (l & 15);
                float* op = (float*)outp;
                #pragma unroll
                for (int r = 0; r < 4; ++r)
                    op[((size_t)img * 256 + co + r) * HW + pix] = fr[r] + bias0[co + r];
            } else {
                int pix = bx * 128 + wm * 64 + m * 16 + (l >> 4) * 4;
                int co  = cobase + wn * 64 + n * 16 + (l & 15);
                if constexpr (MODE == 0) {
                    bf16_t* op = (bf16_t*)outp;
                    float bv = bias0[co];
                    #pragma unroll
                    for (int r = 0; r < 4; ++r) {
                        int p = pix + r;
                        float vv = fr[r] + bv;
                        if (mask[(size_t)img * HW + p]) vv = 0.f;
                        op[((size_t)img * HW + p) * 256 + co] = (bf16_t)vv;
                    }
                } else {
                    if (co < 288) {
                        f16_t* op = (f16_t*)outp;
                        float bv = (co < 192) ? bias0[co] : bias1[co - 192];
                        #pragma unroll
                        for (int r = 0; r < 4; ++r)
                            op[((size_t)img * HW + pix + r) * 288 + co] = (f16_t)(fr[r] + bv);
                    }
                }
            }
        }
}

// ---------------------------------------------------------------------------
// Deformable sampling core, vectorized gathers.
// 256 threads = 32 channel-octets (oct=tid&31: ch oct*8..+7) x 8 query-
// subgroups (qsub=tid>>5), QB=16 queries/block (2 per qsub).
// Per corner: 32 lanes x 16B = full 256-ch row (512B) in ONE load inst.
// value bf16 [12][4096][256]; offattn f16 [4][4096][288]; out: padded NHWC
// bf16 [4][66*66][256] (interior only; borders pre-zeroed).
// ---------------------------------------------------------------------------
__global__ __launch_bounds__(256) void msda_core_kernel(
    const bf16_t* __restrict__ value,
    const f16_t* __restrict__ offattn,
    const float* __restrict__ refp,
    bf16_t* __restrict__ outpad)
{
    constexpr int QB = 16;
    const int n    = blockIdx.y;
    const int q0   = blockIdx.x * QB;
    const int tid  = threadIdx.x;
    const int oct  = tid & 31;
    const int qsub = tid >> 5;
    const int hd   = oct >> 2;

    __shared__ float s_oa[QB][288];
    __shared__ float s_ref[QB][6];
    __shared__ float s_aw[QB][96];

    for (int e = tid; e < QB * 288; e += 256) {
        int qq = e / 288, c = e % 288;
        s_oa[qq][c] = (float)offattn[((size_t)n * HW + q0 + qq) * 288 + c];
    }
    if (tid < QB * 6) {
        int qq = tid / 6, r = tid % 6;
        s_ref[qq][r] = refp[((size_t)n * HW + q0 + qq) * 6 + r];
    }
    __syncthreads();

    // softmax over L*P=12 per (query, head): QB*8 = 128 workers
    if (tid < QB * 8) {
        int qq = tid >> 3, h = tid & 7;
        const float* a = &s_oa[qq][192 + h * 12];
        float mx = a[0];
        #pragma unroll
        for (int k = 1; k < 12; ++k) mx = fmaxf(mx, a[k]);
        float e[12]; float sum = 0.f;
        #pragma unroll
        for (int k = 0; k < 12; ++k) { e[k] = __expf(a[k] - mx); sum += e[k]; }
        float inv = 1.f / sum;
        #pragma unroll
        for (int k = 0; k < 12; ++k) s_aw[qq][h * 12 + k] = e[k] * inv;
    }
    __syncthreads();

    float acc[2][8];
    #pragma unroll
    for (int qi = 0; qi < 2; ++qi)
        #pragma unroll
        for (int j = 0; j < 8; ++j) acc[qi][j] = 0.f;

    const bf16x8 zero8 = {};

    #pragma unroll
    for (int qi = 0; qi < 2; ++qi) {
        const int qq = qsub * 2 + qi;
        #pragma unroll
        for (int ll = 0; ll < 3; ++ll) {
            const bf16_t* vbase = value + ((size_t)(n * 3 + ll) * HW) * 256 + oct * 8;
            float rx = s_ref[qq][ll * 2 + 0] * 64.f - 0.5f;
            float ry = s_ref[qq][ll * 2 + 1] * 64.f - 0.5f;
            #pragma unroll
            for (int p = 0; p < 4; ++p) {
                int idx = hd * 12 + ll * 4 + p;
                float x = rx + s_oa[qq][idx * 2 + 0];
                float y = ry + s_oa[qq][idx * 2 + 1];
                float aw = s_aw[qq][idx];
                float xf = floorf(x), yf = floorf(y);
                float lx = x - xf, ly = y - yf;
                int xi = (int)xf, yi = (int)yf;
                float w00 = (1.f - lx) * (1.f - ly) * aw;
                float w10 = lx * (1.f - ly) * aw;
                float w01 = (1.f - lx) * ly * aw;
                float w11 = lx * ly * aw;
                bool vx0 = (xi >= 0) && (xi < 64);
                bool vx1 = (xi + 1 >= 0) && (xi + 1 < 64);
                bool vy0 = (yi >= 0) && (yi < 64);
                bool vy1 = (yi + 1 >= 0) && (yi + 1 < 64);
                bf16x8 g00 = (vy0 && vx0) ? *(const bf16x8*)(vbase + (size_t)(yi * 64 + xi) * 256)           : zero8;
                bf16x8 g10 = (vy0 && vx1) ? *(const bf16x8*)(vbase + (size_t)(yi * 64 + xi + 1) * 256)       : zero8;
                bf16x8 g01 = (vy1 && vx0) ? *(const bf16x8*)(vbase + (size_t)((yi + 1) * 64 + xi) * 256)     : zero8;
                bf16x8 g11 = (vy1 && vx1) ? *(const bf16x8*)(vbase + (size_t)((yi + 1) * 64 + xi + 1) * 256) : zero8;
                #pragma unroll
                for (int j = 0; j < 8; ++j) {
                    float s = w00 * (float)g00[j] + w10 * (float)g10[j]
                            + w01 * (float)g01[j] + w11 * (float)g11[j];
                    acc[qi][j] += s;
                }
            }
        }
    }

    #pragma unroll
    for (int qi = 0; qi < 2; ++qi) {
        const int qq = qsub * 2 + qi;
        int pix = q0 + qq;
        int pp = ((pix >> 6) + 1) * 66 + (pix & 63) + 1;
        bf16_t tmp[8];
        #pragma unroll
        for (int j = 0; j < 8; ++j) tmp[j] = (bf16_t)acc[qi][j];
        *(bf16x8*)&outpad[((size_t)n * 4356 + pp) * 256 + oct * 8] = *(bf16x8*)tmp;
    }
}

extern "C" void kernel_launch(void* const* d_in, const int* in_sizes, int n_in,
                              void* d_out, int out_size, void* d_ws, size_t ws_size,
                              hipStream_t stream) {
    const float* query   = (const float*)d_in[0];
    const float* refp    = (const float*)d_in[1];
    const float* inflat  = (const float*)d_in[2];
    const unsigned char* mask = (const unsigned char*)d_in[5];
    const float* w_value = (const float*)d_in[6];
    const float* b_value = (const float*)d_in[7];
    const float* w_off   = (const float*)d_in[8];
    const float* b_off   = (const float*)d_in[9];
    const float* w_attn  = (const float*)d_in[10];
    const float* b_attn  = (const float*)d_in[11];
    const float* w_out   = (const float*)d_in[12];
    const float* b_out   = (const float*)d_in[13];

    char* ws = (char*)d_ws;
    bf16_t* A_val  = (bf16_t*)ws;  ws += (size_t)12 * 4356 * 256 * 2;  // 26.76 MB
    bf16_t* A_qry  = (bf16_t*)ws;  ws += (size_t)4 * 4356 * 768 * 2;   // 26.76 MB
    bf16_t* A_core = (bf16_t*)ws;  ws += (size_t)4 * 4356 * 256 * 2;   // 8.92 MB
    size_t pad_bytes = (size_t)(12 * 4356 * 256 + 4 * 4356 * 768 + 4 * 4356 * 256) * 2;
    bf16_t* W_val  = (bf16_t*)ws;  ws += (size_t)9 * 256 * 256 * 2;
    bf16_t* W_off  = (bf16_t*)ws;  ws += (size_t)9 * 384 * 768 * 2;    // COPAD=384
    bf16_t* W_out  = (bf16_t*)ws;  ws += (size_t)9 * 256 * 256 * 2;
    f16_t*  offattn = (f16_t*)ws;  ws += (size_t)4 * 4096 * 288 * 2;   // 9.44 MB
    bf16_t* value  = A_qry;  // reuse: off-conv consumes A_qry before value conv writes
    // total ws ~ 80.5 MiB (< 86 MiB proven available by round 1)

    hipMemsetAsync(d_ws, 0, pad_bytes, stream);

    prep_w<<<(256 * 256 + 255) / 256, 256, 0, stream>>>(w_value, nullptr, W_val, 256, 256, 256, 256);
    prep_w<<<(384 * 768 + 255) / 256, 256, 0, stream>>>(w_off, w_attn, W_off, 768, 192, 288, 384);
    prep_w<<<(256 * 256 + 255) / 256, 256, 0, stream>>>(w_out, nullptr, W_out, 256, 256, 256, 256);

    pad_nchw_to_nhwc<<<dim3(64, 4, 12), 256, 0, stream>>>(inflat, A_val, 256);
    pad_nchw_to_nhwc<<<dim3(64, 12, 4), 256, 0, stream>>>(query,  A_qry, 768);

    mfma_conv<768, 1><<<dim3(32, 3, 4),  256, 0, stream>>>(A_qry, W_off, b_off, b_attn, nullptr, offattn);
    mfma_conv<256, 0><<<dim3(32, 2, 12), 256, 0, stream>>>(A_val, W_val, b_value, nullptr, mask, value);

    msda_core_kernel<<<dim3(HW / 16, 4), 256, 0, stream>>>(value, offattn, refp, A_core);

    mfma_conv<256, 2><<<dim3(32, 2, 4),  256, 0, stream>>>(A_core, W_out, b_out, nullptr, nullptr, d_out);
}